// Round 1
// 1348.356 us; speedup vs baseline: 1.0016x; 1.0016x over previous
//
#include <hip/hip_runtime.h>

#define T_STEPS 20
#define NB      64
#define CIN     12
#define LLEN    4096
#define C1N     64
#define C2N     64
#define TL      128
#define NTHR    512          // 8 waves: wc = wave&3 (c-tile), wl = wave>>2 (l-half)
#define NT2     256
#define XROWS   (TL + 4)     // 132 x rows, block l in [-2, TL+2)
#define NELEM   (CIN * XROWS)
#define NLD     4            // ceil(1584/512) staged loads per thread
#define S1ROWS  (TL + 2)     // 130 spike rows, block l in [-1, TL+1)
#define S1PITCH 72
#define TXL     256

// ---- ws layout ----
#define W1T_OFF_F   0                     // float [36][64]
#define POOL_OFF_F  2304                  // float [64][64]
#define W2BF_OFF_B  25600                 // ushort [2 hilo][3 dk][c2][ci]
#define XT_OFF_B    (1u << 20)            // float [b][ci][t][l]
#define XT_BYTES    ((size_t)NB * CIN * T_STEPS * LLEN * 4)
#define WS_NEED_B   ((size_t)XT_OFF_B + XT_BYTES)

using bf16x8 = __attribute__((ext_vector_type(8))) short;
using f32x4  = __attribute__((ext_vector_type(4))) float;

__device__ inline unsigned short f32_to_bf16_rne(float f) {
    unsigned u = __builtin_bit_cast(unsigned, f);
    return (unsigned short)((u + 0x7FFFu + ((u >> 16) & 1u)) >> 16);
}

__global__ __launch_bounds__(NT2) void prep_weights(
    const float* __restrict__ w1, const float* __restrict__ w2,
    float* __restrict__ ws)
{
    int i = blockIdx.x * NT2 + threadIdx.x;
    float* w1t = ws + W1T_OFF_F;
    unsigned short* w2b = (unsigned short*)((char*)ws + W2BF_OFF_B);
    if (i < C1N * CIN * 3) {
        int c1 = i / (CIN * 3), r = i % (CIN * 3);
        w1t[r * C1N + c1] = w1[i];
    }
    if (i < C2N * C1N * 3) {
        int dk = i % 3, rem = i / 3;
        int ci = rem % C1N, c2 = rem / C1N;
        float w = w2[i];
        unsigned short hi = f32_to_bf16_rne(w);
        float hif = __builtin_bit_cast(float, (unsigned)hi << 16);
        unsigned short lo = f32_to_bf16_rne(w - hif);
        w2b[((0 * 3 + dk) * C2N + c2) * C1N + ci] = hi;
        w2b[((1 * 3 + dk) * C2N + c2) * C1N + ci] = lo;
    }
}

__global__ __launch_bounds__(NT2) void transpose_x(
    const float* __restrict__ xg, float* __restrict__ xt)
{
    __shared__ float tile[TXL * 21];
    const int tid = threadIdx.x;
    const int l0  = blockIdx.x * TXL;
    const int bci = blockIdx.y;
    const float* src = xg + ((size_t)bci * LLEN + l0) * T_STEPS;
#pragma unroll
    for (int k = 0; k < TXL * T_STEPS / NT2; ++k) {
        int e = tid + k * NT2;
        tile[(e / T_STEPS) * 21 + (e % T_STEPS)] = src[e];
    }
    __syncthreads();
    float* dst = xt + (size_t)bci * T_STEPS * LLEN + l0;
#pragma unroll
    for (int t = 0; t < T_STEPS; ++t)
        dst[(size_t)t * LLEN + tid] = tile[tid * 21 + t];
}

// ---------------------------------------------------------------------------
// Main kernel, pipelined. 8 waves/block: wave (wc,wl) owns channels
// [16wc,16wc+16) x l-half wl. x(t+1) is prefetched into registers during
// compute of t; xs is ping-ponged; 2 barriers per t-step.
// waves_per_eu(4,4): pin register budget to 128 VGPRs (2 blocks/CU) so the
// conv2 B-fragments (bw: 48 VGPRs) stay resident instead of spilling to
// scratch (the 64-VGPR/8-wave target spilled them: 197 MB WRITE_SIZE and a
// ~48-load scratch reload chain in every t-step's MFMA phase).
// ---------------------------------------------------------------------------
__global__ __launch_bounds__(NTHR) __attribute__((amdgpu_waves_per_eu(4, 4)))
void snn_main(
    const float* __restrict__ xg, const float* __restrict__ xt, int use_xt,
    const float* __restrict__ b1g, const float* __restrict__ b2g,
    const float* __restrict__ gp, const float* __restrict__ t1p,
    const float* __restrict__ t2p,
    const float* __restrict__ ws, float* __restrict__ pooled)
{
    __shared__ __align__(16) float          xs[2][CIN][XROWS];
    __shared__ __align__(16) unsigned short s1t[S1ROWS][S1PITCH];

    const int tid  = threadIdx.x;
    const int lane = tid & 63;
    const int wv   = __builtin_amdgcn_readfirstlane(tid >> 6);
    const int wc   = wv & 3, wl = wv >> 2;
    const int cb   = wc * 16;
    const int b    = blockIdx.y;
    const int l0   = blockIdx.x * TL;

    const float gain = gp[0], th1 = t1p[0], th2 = t2p[0];
    const float* __restrict__ wT1 = ws + W1T_OFF_F;
    const unsigned short* __restrict__ w2b =
        (const unsigned short*)((const char*)ws + W2BF_OFF_B);

    // conv2 B fragments (hi/lo) in registers
    bf16x8 bw[2][3][2];
    {
        int c2  = cb + (lane & 15);
        int ci0 = ((lane >> 4) & 3) * 8;
#pragma unroll
        for (int h = 0; h < 2; ++h)
#pragma unroll
            for (int dk = 0; dk < 3; ++dk)
#pragma unroll
                for (int cc = 0; cc < 2; ++cc)
                    bw[h][dk][cc] = *(const bf16x8*)
                        (w2b + (((h * 3 + dk) * C2N + c2) * C1N + cc * 32 + ci0));
    }
    const float b2v = b2g[cb + (lane & 15)];

    // b1 is wave-uniform (cb is scalar): pin to SGPRs, zero VGPR cost
    float b1v[16];
#pragma unroll
    for (int j = 0; j < 16; ++j)
        b1v[j] = __builtin_bit_cast(float,
                     __builtin_amdgcn_readfirstlane(
                         __builtin_bit_cast(int, b1g[cb + j])));

    // LIF state: 64 l x 16 c2 per wave -> [4 lt][4 r]
    float v2s[4][4], accs[4][4];
#pragma unroll
    for (int lt = 0; lt < 4; ++lt)
#pragma unroll
        for (int r = 0; r < 4; ++r) { v2s[lt][r] = 0.f; accs[lt][r] = 0.f; }

    // ---- staging: precompute per-thread offsets, prefetch into pf[] ----
    const size_t xbase = (size_t)b * CIN * LLEN * T_STEPS;
    const float* __restrict__ srcp =
        use_xt ? (xt + (size_t)b * CIN * T_STEPS * LLEN) : (xg + xbase);
    const unsigned tstep = use_xt ? (unsigned)LLEN : 1u;

    unsigned off[NLD];          // element offsets, max ~983K: fits u32
    bool   ldok[NLD], gok[NLD];
    float  pf[NLD];
#pragma unroll
    for (int k = 0; k < NLD; ++k) {
        int i  = tid + k * NTHR;
        bool w = i < NELEM;
        int iv = w ? i : 0;
        int ci = iv / XROWS, p = iv - ci * XROWS;
        int gl = l0 - 2 + p;
        bool g = w && ((unsigned)gl < (unsigned)LLEN);
        int glc = g ? gl : 0;
        off[k]  = use_xt ? (unsigned)(ci * T_STEPS * LLEN + glc)
                         : (unsigned)((ci * LLEN + glc) * T_STEPS);
        ldok[k] = w; gok[k] = g;
    }
    float* __restrict__ xsf0 = &xs[0][0][0];
    float* __restrict__ xsf1 = &xs[1][0][0];

    // preamble: pf <- x(0); xs[0] <- pf; pf <- x(1)
#pragma unroll
    for (int k = 0; k < NLD; ++k)
        pf[k] = gok[k] ? srcp[off[k]] : 0.f;
#pragma unroll
    for (int k = 0; k < NLD; ++k)
        if (ldok[k]) xsf0[tid + k * NTHR] = pf[k];
#pragma unroll
    for (int k = 0; k < NLD; ++k)
        pf[k] = gok[k] ? srcp[off[k] + tstep] : 0.f;
    __syncthreads();

    const int m16 = lane & 15;
    const int q8  = ((lane >> 4) & 3) * 8;

#pragma unroll 1
    for (int t = 0; t < T_STEPS; ++t) {
        const float* __restrict__ xc = &xs[t & 1][0][0];

        // ---- conv1 (fp32 VALU, bit-exact): rows wl*64 .. wl*64+63 ----
        {
            int sl = wl * 64 + lane;
            float a1[16];
#pragma unroll
            for (int j = 0; j < 16; ++j) a1[j] = b1v[j];
#pragma unroll 4
            for (int ci = 0; ci < CIN; ++ci) {
                const float* xr = xc + ci * XROWS + sl;
                float x0 = xr[0], x1 = xr[1], x2 = xr[2];
                const float* w0 = wT1 + (ci * 3 + 0) * C1N + cb;
                const float* w1 = wT1 + (ci * 3 + 1) * C1N + cb;
                const float* w2 = wT1 + (ci * 3 + 2) * C1N + cb;
#pragma unroll
                for (int j = 0; j < 16; ++j) {
                    a1[j] = fmaf(w0[j], x0, a1[j]);
                    a1[j] = fmaf(w1[j], x1, a1[j]);
                    a1[j] = fmaf(w2[j], x2, a1[j]);
                }
            }
            int  gls   = l0 - 1 + sl;
            bool valid = (unsigned)gls < (unsigned)LLEN;
            unsigned* dstw = (unsigned*)&s1t[sl][cb];
#pragma unroll
            for (int j = 0; j < 8; ++j) {
                unsigned s0 = (valid && (a1[2*j]   * gain >= th1)) ? 0x3F80u : 0u;
                unsigned s1 = (valid && (a1[2*j+1] * gain >= th1)) ? 0x3F80u : 0u;
                dstw[j] = s0 | (s1 << 16);
            }
        }
        // ---- halo rows 128,129 (wl==0 waves, scalar per (row,ch)) ----
        if (wl == 0 && lane < 32) {
            int row = TL + (lane & 1);
            int ch  = cb + (lane >> 1);
            int gls = l0 - 1 + row;
            bool valid = (unsigned)gls < (unsigned)LLEN;
            float a = b1g[ch];
#pragma unroll
            for (int ci = 0; ci < CIN; ++ci)
#pragma unroll
                for (int k = 0; k < 3; ++k)
                    a = fmaf(wT1[(ci * 3 + k) * C1N + ch], xc[ci * XROWS + row + k], a);
            s1t[row][ch] = (valid && (a * gain >= th1)) ? 0x3F80u : 0u;
        }
        __syncthreads();

        // ---- conv2 (MFMA) + LIF; wave's l-range: wl*64 .. wl*64+63 ----
#pragma unroll
        for (int lt = 0; lt < 4; ++lt) {
            f32x4 d = {0.f, 0.f, 0.f, 0.f};
#pragma unroll
            for (int dk = 0; dk < 3; ++dk) {
                int row = wl * 64 + lt * 16 + m16 + dk;
#pragma unroll
                for (int cc = 0; cc < 2; ++cc) {
                    bf16x8 a = *(const bf16x8*)&s1t[row][cc * 32 + q8];
                    d = __builtin_amdgcn_mfma_f32_16x16x32_bf16(a, bw[0][dk][cc], d, 0, 0, 0);
                    d = __builtin_amdgcn_mfma_f32_16x16x32_bf16(a, bw[1][dk][cc], d, 0, 0, 0);
                }
            }
#pragma unroll
            for (int r = 0; r < 4; ++r) {
                float i2 = (d[r] + b2v) * gain;
                float v  = v2s[lt][r] + (i2 - v2s[lt][r]) * (1.0f / 0.9f);
                bool  sp = v >= th2;
                v2s[lt][r]   = sp ? 0.f : v;
                accs[lt][r] += sp ? 1.f : 0.f;
            }
        }

        // ---- write staged x(t+1), issue loads for x(t+2) ----
        if (t < T_STEPS - 1) {
            float* __restrict__ xn = (t & 1) ? xsf0 : xsf1;
#pragma unroll
            for (int k = 0; k < NLD; ++k)
                if (ldok[k]) xn[tid + k * NTHR] = pf[k];
            if (t < T_STEPS - 2) {
#pragma unroll
                for (int k = 0; k < NLD; ++k)
                    pf[k] = gok[k] ? srcp[off[k] + (size_t)(t + 2) * tstep] : 0.f;
            }
        }
        __syncthreads();
    }

    // ---- reduce acc; lanes L, L+16, L+32, L+48 share c2 ----
    float s = 0.f;
#pragma unroll
    for (int lt = 0; lt < 4; ++lt)
#pragma unroll
        for (int r = 0; r < 4; ++r) s += accs[lt][r];
    s += __shfl_down(s, 32, 64);
    s += __shfl_down(s, 16, 64);
    if (lane < 16) atomicAdd(&pooled[b * C2N + cb + lane], s);
}

__global__ __launch_bounds__(NT2) void fc_kernel(
    const float* __restrict__ pooled, const float* __restrict__ fcw,
    const float* __restrict__ fcb, float* __restrict__ out)
{
    int i = threadIdx.x, b = i >> 2, cls = i & 3;
    float s = 0.f;
#pragma unroll 8
    for (int c = 0; c < C2N; ++c)
        s += pooled[b * C2N + c] * fcw[cls * C2N + c];
    out[b * 4 + cls] = s * (1.0f / ((float)T_STEPS * (float)LLEN)) + fcb[cls];
}

extern "C" void kernel_launch(void* const* d_in, const int* in_sizes, int n_in,
                              void* d_out, int out_size, void* d_ws, size_t ws_size,
                              hipStream_t stream)
{
    const float* xg  = (const float*)d_in[0];
    const float* w1  = (const float*)d_in[1];
    const float* b1  = (const float*)d_in[2];
    const float* w2  = (const float*)d_in[3];
    const float* b2  = (const float*)d_in[4];
    const float* gp  = (const float*)d_in[5];
    const float* t1  = (const float*)d_in[6];
    const float* t2  = (const float*)d_in[7];
    const float* fcw = (const float*)d_in[8];
    const float* fcb = (const float*)d_in[9];
    float* ws  = (float*)d_ws;
    float* out = (float*)d_out;

    const int use_xt = (ws_size >= WS_NEED_B) ? 1 : 0;
    float* xt = (float*)((char*)d_ws + XT_OFF_B);

    hipMemsetAsync(ws + POOL_OFF_F, 0, NB * C2N * sizeof(float), stream);
    prep_weights<<<(C2N * C1N * 3 + NT2 - 1) / NT2, NT2, 0, stream>>>(w1, w2, ws);
    if (use_xt)
        transpose_x<<<dim3(LLEN / TXL, NB * CIN), NT2, 0, stream>>>(xg, xt);
    snn_main<<<dim3(LLEN / TL, NB), NTHR, 0, stream>>>(xg, xt, use_xt,
                                                       b1, b2, gp, t1, t2,
                                                       ws, ws + POOL_OFF_F);
    fc_kernel<<<1, NT2, 0, stream>>>(ws + POOL_OFF_F, fcw, fcb, out);
}

// Round 2
// 1341.063 us; speedup vs baseline: 1.0071x; 1.0054x over previous
//
#include <hip/hip_runtime.h>

#define T_STEPS 20
#define NB      64
#define CIN     12
#define LLEN    4096
#define C1N     64
#define C2N     64
#define TL      128
#define NTHR    512          // 8 waves: wc = wave&3 (c-tile), wl = wave>>2 (l-half)
#define NT2     256
#define XROWS   (TL + 4)     // 132 x rows, block l in [-2, TL+2)
#define NELEM   (CIN * XROWS)
#define NLD     4            // ceil(1584/512) staged loads per thread
#define S1ROWS  (TL + 2)     // 130 spike rows, block l in [-1, TL+1)
#define S1PITCH 72
#define TXL     256

// ---- ws layout ----
#define W1T_OFF_F   0                     // float [36][64]
#define POOL_OFF_F  2304                  // float [64][64]
#define W2BF_OFF_B  25600                 // ushort [2 hilo][3 dk][c2][ci]
#define XT_OFF_B    (1u << 20)            // float [b][ci][t][l]
#define XT_BYTES    ((size_t)NB * CIN * T_STEPS * LLEN * 4)
#define WS_NEED_B   ((size_t)XT_OFF_B + XT_BYTES)

using bf16x8 = __attribute__((ext_vector_type(8))) short;
using f32x4  = __attribute__((ext_vector_type(4))) float;

__device__ inline unsigned short f32_to_bf16_rne(float f) {
    unsigned u = __builtin_bit_cast(unsigned, f);
    return (unsigned short)((u + 0x7FFFu + ((u >> 16) & 1u)) >> 16);
}

__global__ __launch_bounds__(NT2) void prep_weights(
    const float* __restrict__ w1, const float* __restrict__ w2,
    float* __restrict__ ws)
{
    int i = blockIdx.x * NT2 + threadIdx.x;
    float* w1t = ws + W1T_OFF_F;
    unsigned short* w2b = (unsigned short*)((char*)ws + W2BF_OFF_B);
    if (i < C1N * CIN * 3) {
        int c1 = i / (CIN * 3), r = i % (CIN * 3);
        w1t[r * C1N + c1] = w1[i];
    }
    if (i < C2N * C1N * 3) {
        int dk = i % 3, rem = i / 3;
        int ci = rem % C1N, c2 = rem / C1N;
        float w = w2[i];
        unsigned short hi = f32_to_bf16_rne(w);
        float hif = __builtin_bit_cast(float, (unsigned)hi << 16);
        unsigned short lo = f32_to_bf16_rne(w - hif);
        w2b[((0 * 3 + dk) * C2N + c2) * C1N + ci] = hi;
        w2b[((1 * 3 + dk) * C2N + c2) * C1N + ci] = lo;
    }
}

__global__ __launch_bounds__(NT2) void transpose_x(
    const float* __restrict__ xg, float* __restrict__ xt)
{
    __shared__ float tile[TXL * 21];
    const int tid = threadIdx.x;
    const int l0  = blockIdx.x * TXL;
    const int bci = blockIdx.y;
    const float* src = xg + ((size_t)bci * LLEN + l0) * T_STEPS;
#pragma unroll
    for (int k = 0; k < TXL * T_STEPS / NT2; ++k) {
        int e = tid + k * NT2;
        tile[(e / T_STEPS) * 21 + (e % T_STEPS)] = src[e];
    }
    __syncthreads();
    float* dst = xt + (size_t)bci * T_STEPS * LLEN + l0;
#pragma unroll
    for (int t = 0; t < T_STEPS; ++t)
        dst[(size_t)t * LLEN + tid] = tile[tid * 21 + t];
}

// ---------------------------------------------------------------------------
// Main kernel. 8 waves/block: wave (wc,wl) owns channels [16wc,16wc+16) x
// l-half wl.
// ONE barrier per t-step: s1t is double-buffered and conv2 runs one step
// behind conv1 (legal because TAU1=1.0 makes conv1's LIF memoryless:
// s1(t) depends only on x(t)). Iteration tt: conv2+LIF consume s1(tt-1)
// from buf[(tt-1)&1] while conv1 produces s1(tt) into buf[tt&1]. MFMA and
// VALU work now share a phase, so the matrix pipe overlaps conv1's FMAs
// across the 4 resident waves/SIMD instead of idling behind a barrier.
// ---------------------------------------------------------------------------
__global__ __launch_bounds__(NTHR) __attribute__((amdgpu_waves_per_eu(4, 4)))
void snn_main(
    const float* __restrict__ xg, const float* __restrict__ xt, int use_xt,
    const float* __restrict__ b1g, const float* __restrict__ b2g,
    const float* __restrict__ gp, const float* __restrict__ t1p,
    const float* __restrict__ t2p,
    const float* __restrict__ ws, float* __restrict__ pooled)
{
    __shared__ __align__(16) float          xs[2][CIN][XROWS];
    __shared__ __align__(16) unsigned short s1t[2][S1ROWS][S1PITCH];

    const int tid  = threadIdx.x;
    const int lane = tid & 63;
    const int wv   = __builtin_amdgcn_readfirstlane(tid >> 6);
    const int wc   = wv & 3, wl = wv >> 2;
    const int cb   = wc * 16;
    const int b    = blockIdx.y;
    const int l0   = blockIdx.x * TL;

    const float gain = gp[0], th1 = t1p[0], th2 = t2p[0];
    const float* __restrict__ wT1 = ws + W1T_OFF_F;
    const unsigned short* __restrict__ w2b =
        (const unsigned short*)((const char*)ws + W2BF_OFF_B);

    // conv2 B fragments (hi/lo) in registers (AGPR side of the unified file)
    bf16x8 bw[2][3][2];
    {
        int c2  = cb + (lane & 15);
        int ci0 = ((lane >> 4) & 3) * 8;
#pragma unroll
        for (int h = 0; h < 2; ++h)
#pragma unroll
            for (int dk = 0; dk < 3; ++dk)
#pragma unroll
                for (int cc = 0; cc < 2; ++cc)
                    bw[h][dk][cc] = *(const bf16x8*)
                        (w2b + (((h * 3 + dk) * C2N + c2) * C1N + cc * 32 + ci0));
    }
    const float b2v = b2g[cb + (lane & 15)];

    // b1 is wave-uniform (cb is scalar): pin to SGPRs
    float b1v[16];
#pragma unroll
    for (int j = 0; j < 16; ++j)
        b1v[j] = __builtin_bit_cast(float,
                     __builtin_amdgcn_readfirstlane(
                         __builtin_bit_cast(int, b1g[cb + j])));

    // LIF state: 64 l x 16 c2 per wave -> [4 lt][4 r]
    float v2s[4][4], accs[4][4];
#pragma unroll
    for (int lt = 0; lt < 4; ++lt)
#pragma unroll
        for (int r = 0; r < 4; ++r) { v2s[lt][r] = 0.f; accs[lt][r] = 0.f; }

    // ---- staging: precompute per-thread offsets, prefetch into pf[] ----
    const size_t xbase = (size_t)b * CIN * LLEN * T_STEPS;
    const float* __restrict__ srcp =
        use_xt ? (xt + (size_t)b * CIN * T_STEPS * LLEN) : (xg + xbase);
    const unsigned tstep = use_xt ? (unsigned)LLEN : 1u;

    unsigned off[NLD];          // element offsets, max ~983K: fits u32
    bool   ldok[NLD], gok[NLD];
    float  pf[NLD];
#pragma unroll
    for (int k = 0; k < NLD; ++k) {
        int i  = tid + k * NTHR;
        bool w = i < NELEM;
        int iv = w ? i : 0;
        int ci = iv / XROWS, p = iv - ci * XROWS;
        int gl = l0 - 2 + p;
        bool g = w && ((unsigned)gl < (unsigned)LLEN);
        int glc = g ? gl : 0;
        off[k]  = use_xt ? (unsigned)(ci * T_STEPS * LLEN + glc)
                         : (unsigned)((ci * LLEN + glc) * T_STEPS);
        ldok[k] = w; gok[k] = g;
    }
    float* __restrict__ xsf0 = &xs[0][0][0];
    float* __restrict__ xsf1 = &xs[1][0][0];

    // preamble: pf <- x(0); xs[0] <- pf; pf <- x(1)
#pragma unroll
    for (int k = 0; k < NLD; ++k)
        pf[k] = gok[k] ? srcp[off[k]] : 0.f;
#pragma unroll
    for (int k = 0; k < NLD; ++k)
        if (ldok[k]) xsf0[tid + k * NTHR] = pf[k];
#pragma unroll
    for (int k = 0; k < NLD; ++k)
        pf[k] = gok[k] ? srcp[off[k] + tstep] : 0.f;
    __syncthreads();

    const int m16 = lane & 15;
    const int q8  = ((lane >> 4) & 3) * 8;

#pragma unroll 1
    for (int tt = 0; tt <= T_STEPS; ++tt) {
        // ---- conv2 (MFMA) + LIF for step tt-1; reads s1t[(tt-1)&1] ----
        if (tt > 0) {
            const unsigned short (*__restrict__ s1p)[S1PITCH] = s1t[(tt - 1) & 1];
#pragma unroll
            for (int lt = 0; lt < 4; ++lt) {
                f32x4 d = {0.f, 0.f, 0.f, 0.f};
#pragma unroll
                for (int dk = 0; dk < 3; ++dk) {
                    int row = wl * 64 + lt * 16 + m16 + dk;
#pragma unroll
                    for (int cc = 0; cc < 2; ++cc) {
                        bf16x8 a = *(const bf16x8*)&s1p[row][cc * 32 + q8];
                        d = __builtin_amdgcn_mfma_f32_16x16x32_bf16(a, bw[0][dk][cc], d, 0, 0, 0);
                        d = __builtin_amdgcn_mfma_f32_16x16x32_bf16(a, bw[1][dk][cc], d, 0, 0, 0);
                    }
                }
#pragma unroll
                for (int r = 0; r < 4; ++r) {
                    float i2 = (d[r] + b2v) * gain;
                    float v  = v2s[lt][r] + (i2 - v2s[lt][r]) * (1.0f / 0.9f);
                    bool  sp = v >= th2;
                    v2s[lt][r]   = sp ? 0.f : v;
                    accs[lt][r] += sp ? 1.f : 0.f;
                }
            }
        }

        // ---- conv1 for step tt; writes s1t[tt&1] ----
        if (tt < T_STEPS) {
            const float* __restrict__ xc = &xs[tt & 1][0][0];
            unsigned short (*__restrict__ s1c)[S1PITCH] = s1t[tt & 1];
            {
                int sl = wl * 64 + lane;
                float a1[16];
#pragma unroll
                for (int j = 0; j < 16; ++j) a1[j] = b1v[j];
#pragma unroll 4
                for (int ci = 0; ci < CIN; ++ci) {
                    const float* xr = xc + ci * XROWS + sl;
                    float x0 = xr[0], x1 = xr[1], x2 = xr[2];
                    const float* w0 = wT1 + (ci * 3 + 0) * C1N + cb;
                    const float* w1 = wT1 + (ci * 3 + 1) * C1N + cb;
                    const float* w2 = wT1 + (ci * 3 + 2) * C1N + cb;
#pragma unroll
                    for (int j = 0; j < 16; ++j) {
                        a1[j] = fmaf(w0[j], x0, a1[j]);
                        a1[j] = fmaf(w1[j], x1, a1[j]);
                        a1[j] = fmaf(w2[j], x2, a1[j]);
                    }
                }
                int  gls   = l0 - 1 + sl;
                bool valid = (unsigned)gls < (unsigned)LLEN;
                unsigned* dstw = (unsigned*)&s1c[sl][cb];
#pragma unroll
                for (int j = 0; j < 8; ++j) {
                    unsigned s0 = (valid && (a1[2*j]   * gain >= th1)) ? 0x3F80u : 0u;
                    unsigned s1 = (valid && (a1[2*j+1] * gain >= th1)) ? 0x3F80u : 0u;
                    dstw[j] = s0 | (s1 << 16);
                }
            }
            // halo rows 128,129 (wl==0 waves, scalar per (row,ch))
            if (wl == 0 && lane < 32) {
                int row = TL + (lane & 1);
                int ch  = cb + (lane >> 1);
                int gls = l0 - 1 + row;
                bool valid = (unsigned)gls < (unsigned)LLEN;
                float a = b1g[ch];
#pragma unroll
                for (int ci = 0; ci < CIN; ++ci)
#pragma unroll
                    for (int k = 0; k < 3; ++k)
                        a = fmaf(wT1[(ci * 3 + k) * C1N + ch], xc[ci * XROWS + row + k], a);
                s1c[row][ch] = (valid && (a * gain >= th1)) ? 0x3F80u : 0u;
            }

            // ---- write staged x(tt+1), issue loads for x(tt+2) ----
            if (tt < T_STEPS - 1) {
                float* __restrict__ xn = (tt & 1) ? xsf0 : xsf1;
#pragma unroll
                for (int k = 0; k < NLD; ++k)
                    if (ldok[k]) xn[tid + k * NTHR] = pf[k];
                if (tt < T_STEPS - 2) {
#pragma unroll
                    for (int k = 0; k < NLD; ++k)
                        pf[k] = gok[k] ? srcp[off[k] + (size_t)(tt + 2) * tstep] : 0.f;
                }
            }
        }
        __syncthreads();
    }

    // ---- reduce acc; lanes L, L+16, L+32, L+48 share c2 ----
    float s = 0.f;
#pragma unroll
    for (int lt = 0; lt < 4; ++lt)
#pragma unroll
        for (int r = 0; r < 4; ++r) s += accs[lt][r];
    s += __shfl_down(s, 32, 64);
    s += __shfl_down(s, 16, 64);
    if (lane < 16) atomicAdd(&pooled[b * C2N + cb + lane], s);
}

__global__ __launch_bounds__(NT2) void fc_kernel(
    const float* __restrict__ pooled, const float* __restrict__ fcw,
    const float* __restrict__ fcb, float* __restrict__ out)
{
    int i = threadIdx.x, b = i >> 2, cls = i & 3;
    float s = 0.f;
#pragma unroll 8
    for (int c = 0; c < C2N; ++c)
        s += pooled[b * C2N + c] * fcw[cls * C2N + c];
    out[b * 4 + cls] = s * (1.0f / ((float)T_STEPS * (float)LLEN)) + fcb[cls];
}

extern "C" void kernel_launch(void* const* d_in, const int* in_sizes, int n_in,
                              void* d_out, int out_size, void* d_ws, size_t ws_size,
                              hipStream_t stream)
{
    const float* xg  = (const float*)d_in[0];
    const float* w1  = (const float*)d_in[1];
    const float* b1  = (const float*)d_in[2];
    const float* w2  = (const float*)d_in[3];
    const float* b2  = (const float*)d_in[4];
    const float* gp  = (const float*)d_in[5];
    const float* t1  = (const float*)d_in[6];
    const float* t2  = (const float*)d_in[7];
    const float* fcw = (const float*)d_in[8];
    const float* fcb = (const float*)d_in[9];
    float* ws  = (float*)d_ws;
    float* out = (float*)d_out;

    const int use_xt = (ws_size >= WS_NEED_B) ? 1 : 0;
    float* xt = (float*)((char*)d_ws + XT_OFF_B);

    hipMemsetAsync(ws + POOL_OFF_F, 0, NB * C2N * sizeof(float), stream);
    prep_weights<<<(C2N * C1N * 3 + NT2 - 1) / NT2, NT2, 0, stream>>>(w1, w2, ws);
    if (use_xt)
        transpose_x<<<dim3(LLEN / TXL, NB * CIN), NT2, 0, stream>>>(xg, xt);
    snn_main<<<dim3(LLEN / TL, NB), NTHR, 0, stream>>>(xg, xt, use_xt,
                                                       b1, b2, gp, t1, t2,
                                                       ws, ws + POOL_OFF_F);
    fc_kernel<<<1, NT2, 0, stream>>>(ws + POOL_OFF_F, fcw, fcb, out);
}

// Round 3
// 925.368 us; speedup vs baseline: 1.4595x; 1.4492x over previous
//
#include <hip/hip_runtime.h>

#define T_STEPS 20
#define NB      64
#define CIN     12
#define LLEN    4096
#define C1N     64
#define C2N     64
#define TL      64
#define NTHR    256          // 4 waves: wave wc owns channels [16wc,16wc+16), all 64 l
#define NT2     256
#define XR      68           // fp32 staging rows: block l in [-2, 66)
#define NELEM   (CIN * XR)   // 816
#define NLD     4            // ceil(816/256)
#define XPR     70           // bf16-plane rows: 68 data + 2 zeroed (tile4 overreach)
#define XPP     56           // u16 pitch: [h 16][m 16][l 16][pad 8] = 112 B (bank-friendly)
#define S1ROWS  66           // spike rows: block l in [-1, 65)
#define S1PITCH 72
#define TXL     256

// ---- ws layout (unchanged) ----
#define W1T_OFF_F   0                     // float [36][64] (legacy, unused by main now)
#define POOL_OFF_F  2304                  // float [64][64]
#define W2BF_OFF_B  25600                 // ushort [2 hilo][3 dk][c2][ci]
#define XT_OFF_B    (1u << 20)            // float [b][ci][t][l]
#define XT_BYTES    ((size_t)NB * CIN * T_STEPS * LLEN * 4)
#define WS_NEED_B   ((size_t)XT_OFF_B + XT_BYTES)

using bf16x8 = __attribute__((ext_vector_type(8))) short;
using f32x4  = __attribute__((ext_vector_type(4))) float;

__device__ inline unsigned short f32_to_bf16_rne(float f) {
    unsigned u = __builtin_bit_cast(unsigned, f);
    return (unsigned short)((u + 0x7FFFu + ((u >> 16) & 1u)) >> 16);
}
__device__ inline float bf16f(unsigned short h) {
    return __builtin_bit_cast(float, (unsigned)h << 16);
}
// 3-way bf16 split: w ~= h + m + l to ~2^-27 relative
__device__ inline void split3(float w, unsigned short& h, unsigned short& m, unsigned short& l) {
    h = f32_to_bf16_rne(w);
    float r1 = w - bf16f(h);
    m = f32_to_bf16_rne(r1);
    float r2 = r1 - bf16f(m);
    l = f32_to_bf16_rne(r2);
}

__global__ __launch_bounds__(NT2) void prep_weights(
    const float* __restrict__ w1, const float* __restrict__ w2,
    float* __restrict__ ws)
{
    int i = blockIdx.x * NT2 + threadIdx.x;
    float* w1t = ws + W1T_OFF_F;
    unsigned short* w2b = (unsigned short*)((char*)ws + W2BF_OFF_B);
    if (i < C1N * CIN * 3) {
        int c1 = i / (CIN * 3), r = i % (CIN * 3);
        w1t[r * C1N + c1] = w1[i];
    }
    if (i < C2N * C1N * 3) {
        int dk = i % 3, rem = i / 3;
        int ci = rem % C1N, c2 = rem / C1N;
        float w = w2[i];
        unsigned short hi = f32_to_bf16_rne(w);
        float hif = bf16f(hi);
        unsigned short lo = f32_to_bf16_rne(w - hif);
        w2b[((0 * 3 + dk) * C2N + c2) * C1N + ci] = hi;
        w2b[((1 * 3 + dk) * C2N + c2) * C1N + ci] = lo;
    }
}

__global__ __launch_bounds__(NT2) void transpose_x(
    const float* __restrict__ xg, float* __restrict__ xt)
{
    __shared__ float tile[TXL * 21];
    const int tid = threadIdx.x;
    const int l0  = blockIdx.x * TXL;
    const int bci = blockIdx.y;
    const float* src = xg + ((size_t)bci * LLEN + l0) * T_STEPS;
#pragma unroll
    for (int k = 0; k < TXL * T_STEPS / NT2; ++k) {
        int e = tid + k * NT2;
        tile[(e / T_STEPS) * 21 + (e % T_STEPS)] = src[e];
    }
    __syncthreads();
    float* dst = xt + (size_t)bci * T_STEPS * LLEN + l0;
#pragma unroll
    for (int t = 0; t < T_STEPS; ++t)
        dst[(size_t)t * LLEN + tid] = tile[tid * 21 + t];
}

// ---------------------------------------------------------------------------
// Main kernel, conv1 on the matrix pipe.
// 4-wave blocks (TL=64): wave wc owns channels [16wc,16wc+16) for all 64 l.
// conv1 = bf16 MFMA with 3-way split of x AND w (6 product passes: hh, hm,
// mh, hl, lh, mm -> residual ~2^-26, spike decisions ~= fp32). Weights live
// in 24 regs of B-fragments -> ZERO scalar-memory traffic in the t-loop
// (the round-2 stall: per-step uniform weight reloads from L2/L3-thrashed
// global, serialized by SMEM/DS lgkmcnt mixing). x is staged fp32 (as
// before) and converted to 3 bf16 LDS planes one step ahead (pipelined).
// K-packing per MFMA: K = tap*16 + ci (ci 12..15 zero); part0 = taps 0|1,
// part1 = tap 2 | zeros. 5 row-tiles {0,16,32,48,52}: tiles 0-3 cover s1
// rows 0..63, tile4 keeps rows 64,65 only (halo) -> no scalar halo path.
// ---------------------------------------------------------------------------
__global__ __launch_bounds__(NTHR) void snn_main(
    const float* __restrict__ xg, const float* __restrict__ xt, int use_xt,
    const float* __restrict__ b1g, const float* __restrict__ b2g,
    const float* __restrict__ gp, const float* __restrict__ t1p,
    const float* __restrict__ t2p, const float* __restrict__ w1g,
    const float* __restrict__ ws, float* __restrict__ pooled)
{
    __shared__ __align__(16) float          xs32[2][NELEM];
    __shared__ __align__(16) unsigned short xsp[2][XPR][XPP];
    __shared__ __align__(16) unsigned short s1t[2][S1ROWS][S1PITCH];

    const int tid  = threadIdx.x;
    const int lane = tid & 63;
    const int wv   = __builtin_amdgcn_readfirstlane(tid >> 6);
    const int cb   = wv * 16;
    const int b    = blockIdx.y;
    const int l0   = blockIdx.x * TL;

    const float gain = gp[0], th1 = t1p[0], th2 = t2p[0];
    const unsigned short* __restrict__ w2b =
        (const unsigned short*)((const char*)ws + W2BF_OFF_B);

    const int m16 = lane & 15;
    const int q8  = ((lane >> 4) & 3) * 8;

    // ---- conv2 B fragments (hi/lo), as before ----
    bf16x8 bw[2][3][2];
    {
        int c2 = cb + m16;
#pragma unroll
        for (int h = 0; h < 2; ++h)
#pragma unroll
            for (int dk = 0; dk < 3; ++dk)
#pragma unroll
                for (int cc = 0; cc < 2; ++cc)
                    bw[h][dk][cc] = *(const bf16x8*)
                        (w2b + (((h * 3 + dk) * C2N + c2) * C1N + cc * 32 + q8));
    }
    const float b2v = b2g[cb + m16];
    const float b1d = b1g[cb + m16];

    // ---- conv1 B fragments: cw[plane h/m/l][part t01/t2], built from raw w1 ----
    bf16x8 cw[3][2];
    {
        int co = cb + m16;
#pragma unroll
        for (int j = 0; j < 8; ++j) {
            int K = q8 + j;
            {   // part 0: K<16 -> tap0 ci=K; K>=16 -> tap1 ci=K-16
                int tap = K >> 4, ci = K & 15;
                float w = (ci < CIN) ? w1g[(co * CIN + ci) * 3 + tap] : 0.f;
                unsigned short h, m, l; split3(w, h, m, l);
                cw[0][0][j] = (short)h; cw[1][0][j] = (short)m; cw[2][0][j] = (short)l;
            }
            {   // part 1: K<12 -> tap2 ci=K; else zero
                float w = (K < CIN) ? w1g[(co * CIN + K) * 3 + 2] : 0.f;
                unsigned short h, m, l; split3(w, h, m, l);
                cw[0][1][j] = (short)h; cw[1][1][j] = (short)m; cw[2][1][j] = (short)l;
            }
        }
    }

    // LIF state: 64 l x 16 c2 per wave
    float v2s[4][4], accs[4][4];
#pragma unroll
    for (int lt = 0; lt < 4; ++lt)
#pragma unroll
        for (int r = 0; r < 4; ++r) { v2s[lt][r] = 0.f; accs[lt][r] = 0.f; }

    // ---- zero-init: xsp rows 68,69 (full) + ci-pad cols 12..15 of all planes ----
    for (int e = tid; e < 112 + 816; e += NTHR) {
        if (e < 112) {
            int buf = e / 56, rem = e % 56, row = 68 + rem / 28, dw = rem % 28;
            *(unsigned*)((char*)&xsp[buf][row][0] + dw * 4) = 0u;
        } else {
            int e2 = e - 112, br = e2 / 6, ds = e2 % 6;
            int buf = br / XR, row = br % XR, pl = ds >> 1, dw = ds & 1;
            *(unsigned*)((char*)&xsp[buf][row][0] + pl * 32 + 24 + dw * 4) = 0u;
        }
    }

    // ---- staging offsets ----
    const float* __restrict__ srcp =
        use_xt ? (xt + (size_t)b * CIN * T_STEPS * LLEN)
               : (xg + (size_t)b * CIN * LLEN * T_STEPS);
    const unsigned tstep = use_xt ? (unsigned)LLEN : 1u;

    unsigned off[NLD];
    bool ldok[NLD], gok[NLD];
    float pf[NLD];
#pragma unroll
    for (int k = 0; k < NLD; ++k) {
        int i  = tid + k * NTHR;
        bool w = i < NELEM;
        int iv = w ? i : 0;
        int ci = iv / XR, rx = iv - ci * XR;
        int gl = l0 - 2 + rx;
        bool g = w && ((unsigned)gl < (unsigned)LLEN);
        int glc = g ? gl : 0;
        off[k]  = use_xt ? (unsigned)(ci * T_STEPS * LLEN + glc)
                         : (unsigned)((ci * LLEN + glc) * T_STEPS);
        ldok[k] = w; gok[k] = g;
    }
    float* __restrict__ xf0 = &xs32[0][0];
    float* __restrict__ xf1 = &xs32[1][0];

    // A-fragment per-lane address pieces (bytes; + tb*112 + plane*32 at use)
    const bool t2z    = q8 >= 16;
    const int  aoff01 = (m16 + (t2z ? 1 : 0)) * 112 + (q8 & 8) * 2;
    const int  aoff2  = (m16 + 2) * 112 + (q8 & 8) * 2;
    const int  zoff   = 68 * 112 + (q8 & 8) * 2;   // zeroed row (plane offset added at use)

    // ---- preamble: stage x0, convert x0, stage x1, prefetch x2 ----
#pragma unroll
    for (int k = 0; k < NLD; ++k) pf[k] = gok[k] ? srcp[off[k]] : 0.f;
#pragma unroll
    for (int k = 0; k < NLD; ++k) if (ldok[k]) xf0[tid + k * NTHR] = pf[k];
#pragma unroll
    for (int k = 0; k < NLD; ++k) pf[k] = gok[k] ? srcp[off[k] + tstep] : 0.f;
    __syncthreads();
    // convert(0): xs32[0] -> xsp[0]
#pragma unroll
    for (int k = 0; k < NLD; ++k) {
        int e = tid + k * NTHR;
        if (e < NELEM) {
            int rx = e / CIN, ci = e - rx * CIN;
            unsigned short h, m, l; split3(xs32[0][ci * XR + rx], h, m, l);
            xsp[0][rx][ci] = h; xsp[0][rx][16 + ci] = m; xsp[0][rx][32 + ci] = l;
        }
    }
#pragma unroll
    for (int k = 0; k < NLD; ++k) if (ldok[k]) xf1[tid + k * NTHR] = pf[k];
#pragma unroll
    for (int k = 0; k < NLD; ++k)
        pf[k] = gok[k] ? srcp[off[k] + 2u * tstep] : 0.f;
    __syncthreads();

#pragma unroll 1
    for (int tt = 0; tt <= T_STEPS; ++tt) {
        // ---- conv2 (MFMA) + LIF for step tt-1 ----
        if (tt > 0) {
            const unsigned short (*__restrict__ s1p)[S1PITCH] = s1t[(tt - 1) & 1];
#pragma unroll
            for (int lt = 0; lt < 4; ++lt) {
                f32x4 d = {0.f, 0.f, 0.f, 0.f};
#pragma unroll
                for (int dk = 0; dk < 3; ++dk) {
                    int row = lt * 16 + m16 + dk;
#pragma unroll
                    for (int cc = 0; cc < 2; ++cc) {
                        bf16x8 a = *(const bf16x8*)&s1p[row][cc * 32 + q8];
                        d = __builtin_amdgcn_mfma_f32_16x16x32_bf16(a, bw[0][dk][cc], d, 0, 0, 0);
                        d = __builtin_amdgcn_mfma_f32_16x16x32_bf16(a, bw[1][dk][cc], d, 0, 0, 0);
                    }
                }
#pragma unroll
                for (int r = 0; r < 4; ++r) {
                    float i2 = (d[r] + b2v) * gain;
                    float v  = v2s[lt][r] + (i2 - v2s[lt][r]) * (1.0f / 0.9f);
                    bool  sp = v >= th2;
                    v2s[lt][r]   = sp ? 0.f : v;
                    accs[lt][r] += sp ? 1.f : 0.f;
                }
            }
        }

        // ---- conv1 (MFMA, 6 passes) for step tt -> s1t[tt&1] ----
        if (tt < T_STEPS) {
            unsigned short (*__restrict__ s1c)[S1PITCH] = s1t[tt & 1];
            const char* xp = (const char*)&xsp[tt & 1][0][0];
#pragma unroll
            for (int ti = 0; ti < 5; ++ti) {
                const int tb = (ti < 4) ? ti * 16 : 52;
                const char* base01 = xp + tb * 112 + aoff01;
                const char* base2  = t2z ? (xp + zoff) : (xp + tb * 112 + aoff2);
                bf16x8 ah01 = *(const bf16x8*)(base01 + 0);
                bf16x8 am01 = *(const bf16x8*)(base01 + 32);
                bf16x8 al01 = *(const bf16x8*)(base01 + 64);
                bf16x8 ah2  = *(const bf16x8*)(base2 + 0);
                bf16x8 am2  = *(const bf16x8*)(base2 + 32);
                bf16x8 al2  = *(const bf16x8*)(base2 + 64);
                f32x4 d = {b1d, b1d, b1d, b1d};
                d = __builtin_amdgcn_mfma_f32_16x16x32_bf16(ah01, cw[0][0], d, 0, 0, 0); // hh
                d = __builtin_amdgcn_mfma_f32_16x16x32_bf16(ah2,  cw[0][1], d, 0, 0, 0);
                d = __builtin_amdgcn_mfma_f32_16x16x32_bf16(ah01, cw[1][0], d, 0, 0, 0); // hm
                d = __builtin_amdgcn_mfma_f32_16x16x32_bf16(ah2,  cw[1][1], d, 0, 0, 0);
                d = __builtin_amdgcn_mfma_f32_16x16x32_bf16(am01, cw[0][0], d, 0, 0, 0); // mh
                d = __builtin_amdgcn_mfma_f32_16x16x32_bf16(am2,  cw[0][1], d, 0, 0, 0);
                d = __builtin_amdgcn_mfma_f32_16x16x32_bf16(ah01, cw[2][0], d, 0, 0, 0); // hl
                d = __builtin_amdgcn_mfma_f32_16x16x32_bf16(ah2,  cw[2][1], d, 0, 0, 0);
                d = __builtin_amdgcn_mfma_f32_16x16x32_bf16(al01, cw[0][0], d, 0, 0, 0); // lh
                d = __builtin_amdgcn_mfma_f32_16x16x32_bf16(al2,  cw[0][1], d, 0, 0, 0);
                d = __builtin_amdgcn_mfma_f32_16x16x32_bf16(am01, cw[1][0], d, 0, 0, 0); // mm
                d = __builtin_amdgcn_mfma_f32_16x16x32_bf16(am2,  cw[1][1], d, 0, 0, 0);
#pragma unroll
                for (int r = 0; r < 4; ++r) {
                    int m  = ((lane >> 4) & 3) * 4 + r;
                    int rs = tb + m;
                    bool keep  = (ti < 4) || (m == 12 || m == 13);
                    bool valid = (unsigned)(l0 - 1 + rs) < (unsigned)LLEN;
                    bool sp    = valid && (d[r] * gain >= th1);
                    if (keep)
                        s1c[rs][cb + m16] = sp ? (unsigned short)0x3F80u : (unsigned short)0u;
                }
            }
        }

        // ---- convert x(tt+1) fp32 -> bf16 planes ----
        if (tt + 1 < T_STEPS) {
            const int nb = (tt + 1) & 1;
#pragma unroll
            for (int k = 0; k < NLD; ++k) {
                int e = tid + k * NTHR;
                if (e < NELEM) {
                    int rx = e / CIN, ci = e - rx * CIN;
                    unsigned short h, m, l; split3(xs32[nb][ci * XR + rx], h, m, l);
                    xsp[nb][rx][ci] = h; xsp[nb][rx][16 + ci] = m; xsp[nb][rx][32 + ci] = l;
                }
            }
        }
        // ---- write staged x(tt+2), issue loads for x(tt+3) ----
        if (tt + 2 < T_STEPS) {
            float* __restrict__ xn = (tt & 1) ? xf1 : xf0;
#pragma unroll
            for (int k = 0; k < NLD; ++k)
                if (ldok[k]) xn[tid + k * NTHR] = pf[k];
        }
        if (tt + 3 < T_STEPS) {
#pragma unroll
            for (int k = 0; k < NLD; ++k)
                pf[k] = gok[k] ? srcp[off[k] + (size_t)(tt + 3) * tstep] : 0.f;
        }
        __syncthreads();
    }

    // ---- reduce acc; lanes L, L+16, L+32, L+48 share c2 ----
    float s = 0.f;
#pragma unroll
    for (int lt = 0; lt < 4; ++lt)
#pragma unroll
        for (int r = 0; r < 4; ++r) s += accs[lt][r];
    s += __shfl_down(s, 32, 64);
    s += __shfl_down(s, 16, 64);
    if (lane < 16) atomicAdd(&pooled[b * C2N + cb + lane], s);
}

__global__ __launch_bounds__(NT2) void fc_kernel(
    const float* __restrict__ pooled, const float* __restrict__ fcw,
    const float* __restrict__ fcb, float* __restrict__ out)
{
    int i = threadIdx.x, b = i >> 2, cls = i & 3;
    float s = 0.f;
#pragma unroll 8
    for (int c = 0; c < C2N; ++c)
        s += pooled[b * C2N + c] * fcw[cls * C2N + c];
    out[b * 4 + cls] = s * (1.0f / ((float)T_STEPS * (float)LLEN)) + fcb[cls];
}

extern "C" void kernel_launch(void* const* d_in, const int* in_sizes, int n_in,
                              void* d_out, int out_size, void* d_ws, size_t ws_size,
                              hipStream_t stream)
{
    const float* xg  = (const float*)d_in[0];
    const float* w1  = (const float*)d_in[1];
    const float* b1  = (const float*)d_in[2];
    const float* w2  = (const float*)d_in[3];
    const float* b2  = (const float*)d_in[4];
    const float* gp  = (const float*)d_in[5];
    const float* t1  = (const float*)d_in[6];
    const float* t2  = (const float*)d_in[7];
    const float* fcw = (const float*)d_in[8];
    const float* fcb = (const float*)d_in[9];
    float* ws  = (float*)d_ws;
    float* out = (float*)d_out;

    const int use_xt = (ws_size >= WS_NEED_B) ? 1 : 0;
    float* xt = (float*)((char*)d_ws + XT_OFF_B);

    hipMemsetAsync(ws + POOL_OFF_F, 0, NB * C2N * sizeof(float), stream);
    prep_weights<<<(C2N * C1N * 3 + NT2 - 1) / NT2, NT2, 0, stream>>>(w1, w2, ws);
    if (use_xt)
        transpose_x<<<dim3(LLEN / TXL, NB * CIN), NT2, 0, stream>>>(xg, xt);
    snn_main<<<dim3(LLEN / TL, NB), NTHR, 0, stream>>>(xg, xt, use_xt,
                                                       b1, b2, gp, t1, t2, w1,
                                                       ws, ws + POOL_OFF_F);
    fc_kernel<<<1, NT2, 0, stream>>>(ws + POOL_OFF_F, fcw, fcb, out);
}

// Round 4
// 779.163 us; speedup vs baseline: 1.7333x; 1.1876x over previous
//
#include <hip/hip_runtime.h>

#define T_STEPS 20
#define NB      64
#define CIN     12
#define LLEN    4096
#define C1N     64
#define C2N     64
#define TL      64
#define NTHR    256          // 4 waves: wave wc owns channels [16wc,16wc+16), all 64 l
#define NT2     256
#define XR      68           // plane rows with data: block l in [-2, 66)
#define NPAIR   (XR * 6)     // 408 (row, ci-pair) staging units
#define CITP    (LLEN * T_STEPS)   // 81920: x stride per ci (xg layout, t innermost)
#define XPR     70           // bf16-plane rows: 68 data + 2 zeroed (tile4 overreach)
#define XPP     56           // u16 pitch: [h 16][m 16][l 16][pad 8] = 112 B
#define S1ROWS  66           // spike rows: block l in [-1, 65)
#define S1PITCH 72

// ---- ws layout ----
#define POOL_OFF_F  2304                  // float [64][64]
#define W2BF_OFF_B  25600                 // ushort [2 hilo][3 dk][c2][ci]

using bf16x8 = __attribute__((ext_vector_type(8))) short;
using f32x4  = __attribute__((ext_vector_type(4))) float;

__device__ inline unsigned short f32_to_bf16_rne(float f) {
    unsigned u = __builtin_bit_cast(unsigned, f);
    return (unsigned short)((u + 0x7FFFu + ((u >> 16) & 1u)) >> 16);
}
__device__ inline float bf16f(unsigned short h) {
    return __builtin_bit_cast(float, (unsigned)h << 16);
}
// 3-way bf16 split: w ~= h + m + l to ~2^-27 relative
__device__ inline void split3(float w, unsigned short& h, unsigned short& m, unsigned short& l) {
    h = f32_to_bf16_rne(w);
    float r1 = w - bf16f(h);
    m = f32_to_bf16_rne(r1);
    float r2 = r1 - bf16f(m);
    l = f32_to_bf16_rne(r2);
}

__global__ __launch_bounds__(NT2) void prep_weights(
    const float* __restrict__ w2, float* __restrict__ ws)
{
    int i = blockIdx.x * NT2 + threadIdx.x;
    unsigned short* w2b = (unsigned short*)((char*)ws + W2BF_OFF_B);
    if (i < C2N * C1N * 3) {
        int dk = i % 3, rem = i / 3;
        int ci = rem % C1N, c2 = rem / C1N;
        float w = w2[i];
        unsigned short hi = f32_to_bf16_rne(w);
        float hif = bf16f(hi);
        unsigned short lo = f32_to_bf16_rne(w - hif);
        w2b[((0 * 3 + dk) * C2N + c2) * C1N + ci] = hi;
        w2b[((1 * 3 + dk) * C2N + c2) * C1N + ci] = lo;
    }
}

// ---------------------------------------------------------------------------
// Main kernel, both convs on the matrix pipe, xg read DIRECTLY (no transpose
// pre-pass: the per-block x footprint is 816*80 B = 65 KB, re-touched for 20
// steps while L2/L3-resident, and staging loads are issued a full t-step
// (~2300 cyc) ahead -> scattered-load latency is covered; the old transpose
// cost ~280 us + 502 MB of HBM traffic).
// pf (x(t+1) in regs) is converted in-register to the 3 bf16 LDS planes --
// the fp32 xs32 LDS round-trip is gone (fewer LDS ops, fewer u16 same-dword
// bank conflicts, -6.5 KB LDS). Plane writes are packed b32 (ci-pairs).
// waves_per_eu(3): cap regs at 170 total so 3 blocks/CU fit (LDS 34.7 KB
// allows 4; round-3 measured 2 blocks = 23% occupancy, register-limited).
// ---------------------------------------------------------------------------
__global__ __launch_bounds__(NTHR) __attribute__((amdgpu_waves_per_eu(3)))
void snn_main(
    const float* __restrict__ xg,
    const float* __restrict__ b1g, const float* __restrict__ b2g,
    const float* __restrict__ gp, const float* __restrict__ t1p,
    const float* __restrict__ t2p, const float* __restrict__ w1g,
    const float* __restrict__ ws, float* __restrict__ pooled)
{
    __shared__ __align__(16) unsigned short xsp[2][XPR][XPP];
    __shared__ __align__(16) unsigned short s1t[2][S1ROWS][S1PITCH];

    const int tid  = threadIdx.x;
    const int lane = tid & 63;
    const int wv   = __builtin_amdgcn_readfirstlane(tid >> 6);
    const int cb   = wv * 16;
    const int b    = blockIdx.y;
    const int l0   = blockIdx.x * TL;

    const float gain = gp[0], th1 = t1p[0], th2 = t2p[0];
    const unsigned short* __restrict__ w2b =
        (const unsigned short*)((const char*)ws + W2BF_OFF_B);

    const int m16 = lane & 15;
    const int q8  = ((lane >> 4) & 3) * 8;

    // ---- conv2 B fragments (hi/lo) ----
    bf16x8 bw[2][3][2];
    {
        int c2 = cb + m16;
#pragma unroll
        for (int h = 0; h < 2; ++h)
#pragma unroll
            for (int dk = 0; dk < 3; ++dk)
#pragma unroll
                for (int cc = 0; cc < 2; ++cc)
                    bw[h][dk][cc] = *(const bf16x8*)
                        (w2b + (((h * 3 + dk) * C2N + c2) * C1N + cc * 32 + q8));
    }
    const float b2v = b2g[cb + m16];
    const float b1d = b1g[cb + m16];

    // ---- conv1 B fragments: cw[plane h/m/l][part t01/t2], from raw w1 ----
    bf16x8 cw[3][2];
    {
        int co = cb + m16;
#pragma unroll
        for (int j = 0; j < 8; ++j) {
            int K = q8 + j;
            {   // part 0: K<16 -> tap0 ci=K; K>=16 -> tap1 ci=K-16
                int tap = K >> 4, ci = K & 15;
                float w = (ci < CIN) ? w1g[(co * CIN + ci) * 3 + tap] : 0.f;
                unsigned short h, m, l; split3(w, h, m, l);
                cw[0][0][j] = (short)h; cw[1][0][j] = (short)m; cw[2][0][j] = (short)l;
            }
            {   // part 1: K<12 -> tap2 ci=K; else zero
                float w = (K < CIN) ? w1g[(co * CIN + K) * 3 + 2] : 0.f;
                unsigned short h, m, l; split3(w, h, m, l);
                cw[0][1][j] = (short)h; cw[1][1][j] = (short)m; cw[2][1][j] = (short)l;
            }
        }
    }

    // LIF state: 64 l x 16 c2 per wave
    float v2s[4][4], accs[4][4];
#pragma unroll
    for (int lt = 0; lt < 4; ++lt)
#pragma unroll
        for (int r = 0; r < 4; ++r) { v2s[lt][r] = 0.f; accs[lt][r] = 0.f; }

    // ---- zero-init: xsp rows 68,69 (full) + ci-pad cols 12..15 of planes ----
    for (int e = tid; e < 112 + 816; e += NTHR) {
        if (e < 112) {
            int buf = e / 56, rem = e % 56, row = 68 + rem / 28, dw = rem % 28;
            *(unsigned*)((char*)&xsp[buf][row][0] + dw * 4) = 0u;
        } else {
            int e2 = e - 112, br = e2 / 6, ds = e2 % 6;
            int buf = br / XR, row = br % XR, pl = ds >> 1, dw = ds & 1;
            *(unsigned*)((char*)&xsp[buf][row][0] + pl * 32 + 24 + dw * 4) = 0u;
        }
    }

    // ---- staging: (row, ci-pair) units; thread handles <=2 pairs ----
    const float* __restrict__ srcp = xg + (size_t)b * CIN * CITP;
    unsigned off2[2];
    int      lds4[2];
    bool     pok[2], gokp[2];
    float    pf[2][2];
#pragma unroll
    for (int k = 0; k < 2; ++k) {
        int e = tid + k * NTHR;
        bool w = e < NPAIR;
        int ev = w ? e : 0;
        int rx = ev / 6, cp = ev - rx * 6;
        int gl = l0 - 2 + rx;
        bool g = w && ((unsigned)gl < (unsigned)LLEN);
        int glc = g ? gl : 0;
        off2[k] = (unsigned)(cp * 2 * CITP + glc * T_STEPS);   // ci = 2*cp
        lds4[k] = rx * 112 + cp * 4;
        pok[k] = w; gokp[k] = g;
    }

    // A-fragment per-lane address pieces (bytes; + tb*112 + plane*32 at use)
    const bool t2z    = q8 >= 16;
    const int  aoff01 = (m16 + (t2z ? 1 : 0)) * 112 + (q8 & 8) * 2;
    const int  aoff2  = (m16 + 2) * 112 + (q8 & 8) * 2;
    const int  zoff   = 68 * 112 + (q8 & 8) * 2;   // zeroed row

    // ---- preamble: pf <- x(0); convert -> xsp[0]; pf <- x(1) ----
#pragma unroll
    for (int k = 0; k < 2; ++k) {
        pf[k][0] = gokp[k] ? srcp[off2[k]] : 0.f;
        pf[k][1] = gokp[k] ? srcp[off2[k] + CITP] : 0.f;
    }
#pragma unroll
    for (int k = 0; k < 2; ++k)
        if (pok[k]) {
            unsigned short h0, m0, e0, h1, m1, e1;
            split3(pf[k][0], h0, m0, e0);
            split3(pf[k][1], h1, m1, e1);
            unsigned* bp = (unsigned*)((char*)&xsp[0][0][0] + lds4[k]);
            bp[0]  = (unsigned)h0 | ((unsigned)h1 << 16);
            bp[8]  = (unsigned)m0 | ((unsigned)m1 << 16);
            bp[16] = (unsigned)e0 | ((unsigned)e1 << 16);
        }
#pragma unroll
    for (int k = 0; k < 2; ++k) {
        pf[k][0] = gokp[k] ? srcp[off2[k] + 1] : 0.f;
        pf[k][1] = gokp[k] ? srcp[off2[k] + CITP + 1] : 0.f;
    }
    __syncthreads();

#pragma unroll 1
    for (int tt = 0; tt <= T_STEPS; ++tt) {
        // ---- convert pf (= x(tt+1)) -> xsp[(tt+1)&1]; then refill pf ----
        if (tt + 1 < T_STEPS) {
            const int nb = (tt + 1) & 1;
#pragma unroll
            for (int k = 0; k < 2; ++k)
                if (pok[k]) {
                    unsigned short h0, m0, e0, h1, m1, e1;
                    split3(pf[k][0], h0, m0, e0);
                    split3(pf[k][1], h1, m1, e1);
                    unsigned* bp = (unsigned*)((char*)&xsp[nb][0][0] + lds4[k]);
                    bp[0]  = (unsigned)h0 | ((unsigned)h1 << 16);
                    bp[8]  = (unsigned)m0 | ((unsigned)m1 << 16);
                    bp[16] = (unsigned)e0 | ((unsigned)e1 << 16);
                }
        }
        if (tt + 2 < T_STEPS) {   // issue early: consumed next iteration
#pragma unroll
            for (int k = 0; k < 2; ++k) {
                pf[k][0] = gokp[k] ? srcp[off2[k] + (unsigned)(tt + 2)] : 0.f;
                pf[k][1] = gokp[k] ? srcp[off2[k] + CITP + (unsigned)(tt + 2)] : 0.f;
            }
        }

        // ---- conv2 (MFMA) + LIF for step tt-1 ----
        if (tt > 0) {
            const unsigned short (*__restrict__ s1p)[S1PITCH] = s1t[(tt - 1) & 1];
#pragma unroll
            for (int lt = 0; lt < 4; ++lt) {
                f32x4 d = {0.f, 0.f, 0.f, 0.f};
#pragma unroll
                for (int dk = 0; dk < 3; ++dk) {
                    int row = lt * 16 + m16 + dk;
#pragma unroll
                    for (int cc = 0; cc < 2; ++cc) {
                        bf16x8 a = *(const bf16x8*)&s1p[row][cc * 32 + q8];
                        d = __builtin_amdgcn_mfma_f32_16x16x32_bf16(a, bw[0][dk][cc], d, 0, 0, 0);
                        d = __builtin_amdgcn_mfma_f32_16x16x32_bf16(a, bw[1][dk][cc], d, 0, 0, 0);
                    }
                }
#pragma unroll
                for (int r = 0; r < 4; ++r) {
                    float i2 = (d[r] + b2v) * gain;
                    float v  = v2s[lt][r] + (i2 - v2s[lt][r]) * (1.0f / 0.9f);
                    bool  sp = v >= th2;
                    v2s[lt][r]   = sp ? 0.f : v;
                    accs[lt][r] += sp ? 1.f : 0.f;
                }
            }
        }

        // ---- conv1 (MFMA, 6 passes) for step tt -> s1t[tt&1] ----
        if (tt < T_STEPS) {
            unsigned short (*__restrict__ s1c)[S1PITCH] = s1t[tt & 1];
            const char* xp = (const char*)&xsp[tt & 1][0][0];
#pragma unroll
            for (int ti = 0; ti < 5; ++ti) {
                const int tb = (ti < 4) ? ti * 16 : 52;
                const char* base01 = xp + tb * 112 + aoff01;
                const char* base2  = t2z ? (xp + zoff) : (xp + tb * 112 + aoff2);
                bf16x8 ah01 = *(const bf16x8*)(base01 + 0);
                bf16x8 am01 = *(const bf16x8*)(base01 + 32);
                bf16x8 al01 = *(const bf16x8*)(base01 + 64);
                bf16x8 ah2  = *(const bf16x8*)(base2 + 0);
                bf16x8 am2  = *(const bf16x8*)(base2 + 32);
                bf16x8 al2  = *(const bf16x8*)(base2 + 64);
                f32x4 d = {b1d, b1d, b1d, b1d};
                d = __builtin_amdgcn_mfma_f32_16x16x32_bf16(ah01, cw[0][0], d, 0, 0, 0); // hh
                d = __builtin_amdgcn_mfma_f32_16x16x32_bf16(ah2,  cw[0][1], d, 0, 0, 0);
                d = __builtin_amdgcn_mfma_f32_16x16x32_bf16(ah01, cw[1][0], d, 0, 0, 0); // hm
                d = __builtin_amdgcn_mfma_f32_16x16x32_bf16(ah2,  cw[1][1], d, 0, 0, 0);
                d = __builtin_amdgcn_mfma_f32_16x16x32_bf16(am01, cw[0][0], d, 0, 0, 0); // mh
                d = __builtin_amdgcn_mfma_f32_16x16x32_bf16(am2,  cw[0][1], d, 0, 0, 0);
                d = __builtin_amdgcn_mfma_f32_16x16x32_bf16(ah01, cw[2][0], d, 0, 0, 0); // hl
                d = __builtin_amdgcn_mfma_f32_16x16x32_bf16(ah2,  cw[2][1], d, 0, 0, 0);
                d = __builtin_amdgcn_mfma_f32_16x16x32_bf16(al01, cw[0][0], d, 0, 0, 0); // lh
                d = __builtin_amdgcn_mfma_f32_16x16x32_bf16(al2,  cw[0][1], d, 0, 0, 0);
                d = __builtin_amdgcn_mfma_f32_16x16x32_bf16(am01, cw[1][0], d, 0, 0, 0); // mm
                d = __builtin_amdgcn_mfma_f32_16x16x32_bf16(am2,  cw[1][1], d, 0, 0, 0);
#pragma unroll
                for (int r = 0; r < 4; ++r) {
                    int m  = ((lane >> 4) & 3) * 4 + r;
                    int rs = tb + m;
                    bool keep  = (ti < 4) || (m == 12 || m == 13);
                    bool valid = (unsigned)(l0 - 1 + rs) < (unsigned)LLEN;
                    bool sp    = valid && (d[r] * gain >= th1);
                    if (keep)
                        s1c[rs][cb + m16] = sp ? (unsigned short)0x3F80u : (unsigned short)0u;
                }
            }
        }
        __syncthreads();
    }

    // ---- reduce acc; lanes L, L+16, L+32, L+48 share c2 ----
    float s = 0.f;
#pragma unroll
    for (int lt = 0; lt < 4; ++lt)
#pragma unroll
        for (int r = 0; r < 4; ++r) s += accs[lt][r];
    s += __shfl_down(s, 32, 64);
    s += __shfl_down(s, 16, 64);
    if (lane < 16) atomicAdd(&pooled[b * C2N + cb + lane], s);
}

__global__ __launch_bounds__(NT2) void fc_kernel(
    const float* __restrict__ pooled, const float* __restrict__ fcw,
    const float* __restrict__ fcb, float* __restrict__ out)
{
    int i = threadIdx.x, b = i >> 2, cls = i & 3;
    float s = 0.f;
#pragma unroll 8
    for (int c = 0; c < C2N; ++c)
        s += pooled[b * C2N + c] * fcw[cls * C2N + c];
    out[b * 4 + cls] = s * (1.0f / ((float)T_STEPS * (float)LLEN)) + fcb[cls];
}

extern "C" void kernel_launch(void* const* d_in, const int* in_sizes, int n_in,
                              void* d_out, int out_size, void* d_ws, size_t ws_size,
                              hipStream_t stream)
{
    const float* xg  = (const float*)d_in[0];
    const float* w1  = (const float*)d_in[1];
    const float* b1  = (const float*)d_in[2];
    const float* w2  = (const float*)d_in[3];
    const float* b2  = (const float*)d_in[4];
    const float* gp  = (const float*)d_in[5];
    const float* t1  = (const float*)d_in[6];
    const float* t2  = (const float*)d_in[7];
    const float* fcw = (const float*)d_in[8];
    const float* fcb = (const float*)d_in[9];
    float* ws  = (float*)d_ws;
    float* out = (float*)d_out;

    hipMemsetAsync(ws + POOL_OFF_F, 0, NB * C2N * sizeof(float), stream);
    prep_weights<<<(C2N * C1N * 3 + NT2 - 1) / NT2, NT2, 0, stream>>>(w2, ws);
    snn_main<<<dim3(LLEN / TL, NB), NTHR, 0, stream>>>(xg,
                                                       b1, b2, gp, t1, t2, w1,
                                                       ws, ws + POOL_OFF_F);
    fc_kernel<<<1, NT2, 0, stream>>>(ws + POOL_OFF_F, fcw, fcb, out);
}